// Round 2
// baseline (1481.321 us; speedup 1.0000x reference)
//
#include <hip/hip_runtime.h>
#include <float.h>

// Problem constants
constexpr int kB = 2, kS = 2048, kSE = 2048, kL = 4096, kHID = 768, kH = 12, kD = 64;

// ---------------------------------------------------------------------------
// Kernel 1: LayerNorm (q and kv) + copy encoder_output into ekv buffer.
// grid = (B*S, 3); block = 256. mode 0: LN(q)->q_hs ; 1: LN(kv)->ekv[:,SE+s,:] ;
// 2: copy enc -> ekv[:, s, :]
// ---------------------------------------------------------------------------
__global__ __launch_bounds__(256) void ln_copy_kernel(
    const float* __restrict__ qin, const float* __restrict__ kvin,
    const float* __restrict__ enc, const float* __restrict__ g,
    const float* __restrict__ beta, float* __restrict__ q_hs,
    float* __restrict__ ekv)
{
  const int row = blockIdx.x;            // b*2048 + s
  const int mode = blockIdx.y;
  const int t = threadIdx.x;
  const int b = row >> 11, s = row & 2047;

  if (mode == 2) {
    const float4* src = (const float4*)(enc + (size_t)row * kHID);
    float4* dst = (float4*)(ekv + ((size_t)b * kL + s) * kHID);
    if (t < 192) dst[t] = src[t];        // 768 floats = 192 float4
    return;
  }

  const float* x = (mode == 0 ? qin : kvin) + (size_t)row * kHID;
  float v0 = x[t], v1 = x[t + 256], v2 = x[t + 512];
  float sum = v0 + v1 + v2;
  float sq  = v0 * v0 + v1 * v1 + v2 * v2;
  #pragma unroll
  for (int off = 32; off > 0; off >>= 1) {
    sum += __shfl_down(sum, off, 64);
    sq  += __shfl_down(sq,  off, 64);
  }
  __shared__ float red[8];
  const int wave = t >> 6;
  if ((t & 63) == 0) { red[wave] = sum; red[wave + 4] = sq; }
  __syncthreads();
  const float tsum = red[0] + red[1] + red[2] + red[3];
  const float tsq  = red[4] + red[5] + red[6] + red[7];
  const float mu   = tsum * (1.0f / kHID);
  const float var  = tsq * (1.0f / kHID) - mu * mu;
  const float rstd = rsqrtf(var + 1e-12f);

  float* out = (mode == 0) ? (q_hs + (size_t)row * kHID)
                           : (ekv + ((size_t)b * kL + kSE + s) * kHID);
  out[t]       = (v0 - mu) * rstd * g[t]       + beta[t];
  out[t + 256] = (v1 - mu) * rstd * g[t + 256] + beta[t + 256];
  out[t + 512] = (v2 - mu) * rstd * g[t + 512] + beta[t + 512];
}

// ---------------------------------------------------------------------------
// Kernel 2/4: fp32 GEMM  C[M,N] = A[M,768] * W[N,768]^T + bias (+ residual)
// 64x64 tile, BK=32, 256 threads, 4x4 register micro-tile.
// MODE 0: scatter into K/V buffers [B][H][L][D].  MODE 1: +bias+residual -> out.
// ---------------------------------------------------------------------------
template <int MODE>
__global__ __launch_bounds__(256) void gemm64(
    const float* __restrict__ A, const float* __restrict__ W,
    const float* __restrict__ bias, float* __restrict__ out0,
    float* __restrict__ out1, const float* __restrict__ resid)
{
  __shared__ float As[32][64];   // k-major
  __shared__ float Bs[32][64];
  const int t = threadIdx.x;
  const int m0 = blockIdx.x * 64, n0 = blockIdx.y * 64;
  const int tx = t & 15, ty = t >> 4;

  float acc[4][4] = {};

  for (int kt = 0; kt < kHID; kt += 32) {
    __syncthreads();
    #pragma unroll
    for (int r = 0; r < 2; r++) {
      const int f = t + r * 256;          // 0..511
      const int row = f >> 3, kc = f & 7;
      float4 va = *(const float4*)(A + (size_t)(m0 + row) * kHID + kt + kc * 4);
      As[kc * 4 + 0][row] = va.x; As[kc * 4 + 1][row] = va.y;
      As[kc * 4 + 2][row] = va.z; As[kc * 4 + 3][row] = va.w;
      float4 vb = *(const float4*)(W + (size_t)(n0 + row) * kHID + kt + kc * 4);
      Bs[kc * 4 + 0][row] = vb.x; Bs[kc * 4 + 1][row] = vb.y;
      Bs[kc * 4 + 2][row] = vb.z; Bs[kc * 4 + 3][row] = vb.w;
    }
    __syncthreads();
    #pragma unroll
    for (int k = 0; k < 32; k++) {
      const float4 a4 = *(const float4*)&As[k][ty * 4];
      const float4 b4 = *(const float4*)&Bs[k][tx * 4];
      const float av[4] = {a4.x, a4.y, a4.z, a4.w};
      const float bv[4] = {b4.x, b4.y, b4.z, b4.w};
      #pragma unroll
      for (int i = 0; i < 4; i++)
        #pragma unroll
        for (int j = 0; j < 4; j++)
          acc[i][j] += av[i] * bv[j];
    }
  }

  const int nb = n0 + tx * 4;
  const float4 bv4 = *(const float4*)(bias + nb);
  const float bvv[4] = {bv4.x, bv4.y, bv4.z, bv4.w};

  if (MODE == 0) {
    // n -> (t, h, d): t = n/768, h = (n%768)/64, d = n%64 ; m -> (b, l)
    const bool isV = nb >= kHID;
    const int nn = isV ? nb - kHID : nb;
    const int h = nn >> 6, d0 = nn & 63;
    float* base = isV ? out1 : out0;
    #pragma unroll
    for (int i = 0; i < 4; i++) {
      const int m = m0 + ty * 4 + i;
      const int b = m >> 12, l = m & 4095;
      float4 o = {acc[i][0] + bvv[0], acc[i][1] + bvv[1],
                  acc[i][2] + bvv[2], acc[i][3] + bvv[3]};
      *(float4*)(base + (((size_t)(b * kH + h)) * kL + l) * kD + d0) = o;
    }
  } else {
    #pragma unroll
    for (int i = 0; i < 4; i++) {
      const int m = m0 + ty * 4 + i;
      const size_t off = (size_t)m * kHID + nb;
      const float4 r4 = *(const float4*)(resid + off);
      float4 o = {acc[i][0] + bvv[0] + r4.x, acc[i][1] + bvv[1] + r4.y,
                  acc[i][2] + bvv[2] + r4.z, acc[i][3] + bvv[3] + r4.w};
      *(float4*)(out0 + off) = o;
    }
  }
}

// ---------------------------------------------------------------------------
// Kernel 3: flash-style attention, fp32 vector ALU.
// grid = (S/64, H, B); block = 256.  Q-tile 64 rows; stream K/V in 64-tiles.
// Score phase: thread (qg,lg) owns 4x4 (q x l). PV phase: thread (qg,dg) owns
// 4x4 (q x d). Online softmax state replicated across the 16 lanes per q-group.
// Qs and Ks are float4-chunk XOR-swizzled by (row>>2) so the score phase's
// broadcast reads land on distinct bank quads (was a 4-way conflict on Qs).
// ---------------------------------------------------------------------------
__global__ __launch_bounds__(256) void attn_kernel(
    const float* __restrict__ q_hs, const float* __restrict__ Kbuf,
    const float* __restrict__ Vbuf, const unsigned char* __restrict__ am,
    const unsigned char* __restrict__ dm, float* __restrict__ attn_out)
{
  __shared__ float Qs[64][64];   // float4-chunk XOR-swizzled by (row>>2)
  __shared__ float Ks[64][64];   // float4-chunk XOR-swizzled by (row>>2)
  __shared__ float Vs[64][64];
  __shared__ float Ps[64][64];   // float4-chunk XOR-swizzled by (q&15)

  const int qt = blockIdx.x, h = blockIdx.y, b = blockIdx.z;
  const int s0 = qt * 64;
  const int t = threadIdx.x;
  const int qg = t >> 4;          // 0..15
  const int lg = t & 15;          // l-group in scores, d-group in PV
  const float scale = 0.125f;     // 1/sqrt(64)

  const float* Kbh = Kbuf + ((size_t)(b * kH + h)) * kL * kD;
  const float* Vbh = Vbuf + ((size_t)(b * kH + h)) * kL * kD;

  // Load Q tile: rows s0..s0+63, dims h*64..h*64+63 (swizzled store)
  #pragma unroll
  for (int r = 0; r < 4; r++) {
    const int f = t + r * 256;    // 0..1023
    const int row = f >> 4, c = f & 15;
    float4 v = *(const float4*)(q_hs + ((size_t)(b * kS + s0 + row)) * kHID + h * kD + c * 4);
    const int cs = c ^ (row >> 2);
    *(float4*)&Qs[row][cs * 4] = v;
  }

  float O[4][4] = {};
  float mrun[4] = {-FLT_MAX, -FLT_MAX, -FLT_MAX, -FLT_MAX};
  float lrun[4] = {};

  for (int lt = 0; lt < kL / 64; lt++) {
    __syncthreads();   // previous PV done with Vs/Ps; also covers initial Q load
    #pragma unroll
    for (int r = 0; r < 4; r++) {
      const int f = t + r * 256;
      const int row = f >> 4, c = f & 15;
      const size_t goff = (size_t)(lt * 64 + row) * kD + c * 4;
      float4 kv = *(const float4*)(Kbh + goff);
      const int cs = c ^ (row >> 2);
      *(float4*)&Ks[row][cs * 4] = kv;
      float4 vv = *(const float4*)(Vbh + goff);
      *(float4*)&Vs[row][c * 4] = vv;
    }
    __syncthreads();

    // ---- scores: 4q x 4l per thread ----
    float sc[4][4] = {};
    #pragma unroll 4
    for (int kc = 0; kc < 16; kc++) {
      float4 qq[4], kk[4];
      #pragma unroll
      for (int i = 0; i < 4; i++) qq[i] = *(const float4*)&Qs[qg * 4 + i][((kc ^ qg) & 15) * 4];
      #pragma unroll
      for (int j = 0; j < 4; j++) kk[j] = *(const float4*)&Ks[lg * 4 + j][((kc ^ lg) & 15) * 4];
      #pragma unroll
      for (int i = 0; i < 4; i++)
        #pragma unroll
        for (int j = 0; j < 4; j++)
          sc[i][j] += qq[i].x * kk[j].x + qq[i].y * kk[j].y +
                      qq[i].z * kk[j].z + qq[i].w * kk[j].w;
    }

    // ---- scale + mask ----
    if (lt >= kSE / 64) {
      const int le0 = lt * 64 - kSE + lg * 4;
      const uchar4 amv = *(const uchar4*)(am + b * kS + le0);
      const unsigned char ama[4] = {amv.x, amv.y, amv.z, amv.w};
      #pragma unroll
      for (int i = 0; i < 4; i++) {
        const int s_ = s0 + qg * 4 + i;
        const uchar4 dmv = *(const uchar4*)(dm + ((size_t)(b * kS + s_)) * kS + le0);
        const unsigned char dma[4] = {dmv.x, dmv.y, dmv.z, dmv.w};
        #pragma unroll
        for (int j = 0; j < 4; j++) {
          const bool valid = ama[j] && dma[j] && (s_ != le0 + j);
          sc[i][j] = valid ? sc[i][j] * scale : -FLT_MAX;
        }
      }
    } else {
      #pragma unroll
      for (int i = 0; i < 4; i++)
        #pragma unroll
        for (int j = 0; j < 4; j++) sc[i][j] *= scale;
    }

    // ---- online softmax (replicated across the 16 lanes of each q-group) ----
    float corr[4];
    #pragma unroll
    for (int i = 0; i < 4; i++) {
      float tm = fmaxf(fmaxf(sc[i][0], sc[i][1]), fmaxf(sc[i][2], sc[i][3]));
      #pragma unroll
      for (int msk = 1; msk < 16; msk <<= 1) tm = fmaxf(tm, __shfl_xor(tm, msk, 64));
      const float mn = fmaxf(mrun[i], tm);
      corr[i] = __expf(mrun[i] - mn);
      mrun[i] = mn;
      float ps = 0.f;
      #pragma unroll
      for (int j = 0; j < 4; j++) { sc[i][j] = __expf(sc[i][j] - mn); ps += sc[i][j]; }
      #pragma unroll
      for (int msk = 1; msk < 16; msk <<= 1) ps += __shfl_xor(ps, msk, 64);
      lrun[i] = lrun[i] * corr[i] + ps;
      const int q = qg * 4 + i;
      float4 p4 = {sc[i][0], sc[i][1], sc[i][2], sc[i][3]};
      *(float4*)&Ps[q][((lg ^ (q & 15)) & 15) * 4] = p4;
    }
    __syncthreads();

    // ---- PV: 4q x 4d per thread (lg acts as dg) ----
    #pragma unroll
    for (int i = 0; i < 4; i++) {
      O[i][0] *= corr[i]; O[i][1] *= corr[i]; O[i][2] *= corr[i]; O[i][3] *= corr[i];
    }
    #pragma unroll 4
    for (int lc = 0; lc < 16; lc++) {
      float4 pp[4];
      #pragma unroll
      for (int i = 0; i < 4; i++) {
        const int q = qg * 4 + i;
        pp[i] = *(const float4*)&Ps[q][((lc ^ (q & 15)) & 15) * 4];
      }
      #pragma unroll
      for (int j = 0; j < 4; j++) {
        const float4 vv = *(const float4*)&Vs[lc * 4 + j][lg * 4];
        const float p0 = (j == 0) ? pp[0].x : (j == 1) ? pp[0].y : (j == 2) ? pp[0].z : pp[0].w;
        const float p1 = (j == 0) ? pp[1].x : (j == 1) ? pp[1].y : (j == 2) ? pp[1].z : pp[1].w;
        const float p2 = (j == 0) ? pp[2].x : (j == 1) ? pp[2].y : (j == 2) ? pp[2].z : pp[2].w;
        const float p3 = (j == 0) ? pp[3].x : (j == 1) ? pp[3].y : (j == 2) ? pp[3].z : pp[3].w;
        O[0][0] += p0 * vv.x; O[0][1] += p0 * vv.y; O[0][2] += p0 * vv.z; O[0][3] += p0 * vv.w;
        O[1][0] += p1 * vv.x; O[1][1] += p1 * vv.y; O[1][2] += p1 * vv.z; O[1][3] += p1 * vv.w;
        O[2][0] += p2 * vv.x; O[2][1] += p2 * vv.y; O[2][2] += p2 * vv.z; O[2][3] += p2 * vv.w;
        O[3][0] += p3 * vv.x; O[3][1] += p3 * vv.y; O[3][2] += p3 * vv.z; O[3][3] += p3 * vv.w;
      }
    }
  }

  // ---- normalize + store ----
  #pragma unroll
  for (int i = 0; i < 4; i++) {
    const float inv = 1.0f / lrun[i];
    const int s_ = s0 + qg * 4 + i;
    float4 o = {O[i][0] * inv, O[i][1] * inv, O[i][2] * inv, O[i][3] * inv};
    *(float4*)(attn_out + ((size_t)(b * kS + s_)) * kHID + h * kD + lg * 4) = o;
  }
}

// ---------------------------------------------------------------------------
extern "C" void kernel_launch(void* const* d_in, const int* in_sizes, int n_in,
                              void* d_out, int out_size, void* d_ws, size_t ws_size,
                              hipStream_t stream) {
  const float* q_in    = (const float*)d_in[0];
  const float* kv_in   = (const float*)d_in[1];
  const float* enc     = (const float*)d_in[2];
  const unsigned char* am = (const unsigned char*)d_in[3];   // bool -> 1 byte
  const unsigned char* dm = (const unsigned char*)d_in[4];   // bool -> 1 byte
  // d_in[5], d_in[6]: Wq (computed-then-discarded in reference) -> skipped
  const float* wkv_w   = (const float*)d_in[7];
  const float* wkv_b   = (const float*)d_in[8];
  const float* dense_w = (const float*)d_in[9];
  const float* dense_b = (const float*)d_in[10];
  const float* norm_g  = (const float*)d_in[11];
  const float* norm_b  = (const float*)d_in[12];
  float* out = (float*)d_out;

  float* ws = (float*)d_ws;
  float* q_hs = ws;                       // [B,S,HID]        3,145,728 f
  float* ekv  = ws + 3145728;             // [B,L,HID]        6,291,456 f
  float* Kbuf = ws + 9437184;             // [B,H,L,D]        6,291,456 f
  float* Vbuf = ws + 15728640;            // [B,H,L,D]        6,291,456 f
  float* attn_out = ekv;                  // alias: ekv dead after KV GEMM

  hipLaunchKernelGGL(ln_copy_kernel, dim3(kB * kS, 3), dim3(256), 0, stream,
                     q_in, kv_in, enc, norm_g, norm_b, q_hs, ekv);
  hipLaunchKernelGGL((gemm64<0>), dim3((kB * kL) / 64, (2 * kHID) / 64), dim3(256), 0, stream,
                     ekv, wkv_w, wkv_b, Kbuf, Vbuf, nullptr);
  hipLaunchKernelGGL(attn_kernel, dim3(kS / 64, kH, kB), dim3(256), 0, stream,
                     q_hs, Kbuf, Vbuf, am, dm, attn_out);
  hipLaunchKernelGGL((gemm64<1>), dim3((kB * kS) / 64, kHID / 64), dim3(256), 0, stream,
                     attn_out, dense_w, dense_b, out, nullptr, q_hs);
}

// Round 3
// 694.835 us; speedup vs baseline: 2.1319x; 2.1319x over previous
//
#include <hip/hip_runtime.h>
#include <float.h>

// Problem constants
constexpr int kB = 2, kS = 2048, kSE = 2048, kL = 4096, kHID = 768, kH = 12, kD = 64;

typedef __attribute__((ext_vector_type(8))) short bfrag;   // 8 bf16 (4 VGPRs)
typedef __attribute__((ext_vector_type(4))) float f32x4;   // 4 fp32 acc

__device__ __forceinline__ short f2bf(float x) {
  unsigned u = __float_as_uint(x);
  u += 0x7fffu + ((u >> 16) & 1u);     // RNE
  return (short)(u >> 16);
}

// ---------------------------------------------------------------------------
// Kernel 1: LayerNorm (q and kv) + copy encoder_output into ekv buffer.
// mode 0 additionally writes a bf16 copy of LN(q) for the MFMA attention.
// ---------------------------------------------------------------------------
__global__ __launch_bounds__(256) void ln_copy_kernel(
    const float* __restrict__ qin, const float* __restrict__ kvin,
    const float* __restrict__ enc, const float* __restrict__ g,
    const float* __restrict__ beta, float* __restrict__ q_hs,
    float* __restrict__ ekv, short* __restrict__ qbf)
{
  const int row = blockIdx.x;            // b*2048 + s
  const int mode = blockIdx.y;
  const int t = threadIdx.x;
  const int b = row >> 11, s = row & 2047;

  if (mode == 2) {
    const float4* src = (const float4*)(enc + (size_t)row * kHID);
    float4* dst = (float4*)(ekv + ((size_t)b * kL + s) * kHID);
    if (t < 192) dst[t] = src[t];        // 768 floats = 192 float4
    return;
  }

  const float* x = (mode == 0 ? qin : kvin) + (size_t)row * kHID;
  float v0 = x[t], v1 = x[t + 256], v2 = x[t + 512];
  float sum = v0 + v1 + v2;
  float sq  = v0 * v0 + v1 * v1 + v2 * v2;
  #pragma unroll
  for (int off = 32; off > 0; off >>= 1) {
    sum += __shfl_down(sum, off, 64);
    sq  += __shfl_down(sq,  off, 64);
  }
  __shared__ float red[8];
  const int wave = t >> 6;
  if ((t & 63) == 0) { red[wave] = sum; red[wave + 4] = sq; }
  __syncthreads();
  const float tsum = red[0] + red[1] + red[2] + red[3];
  const float tsq  = red[4] + red[5] + red[6] + red[7];
  const float mu   = tsum * (1.0f / kHID);
  const float var  = tsq * (1.0f / kHID) - mu * mu;
  const float rstd = rsqrtf(var + 1e-12f);

  const float o0 = (v0 - mu) * rstd * g[t]       + beta[t];
  const float o1 = (v1 - mu) * rstd * g[t + 256] + beta[t + 256];
  const float o2 = (v2 - mu) * rstd * g[t + 512] + beta[t + 512];

  if (mode == 0) {
    float* out = q_hs + (size_t)row * kHID;
    out[t] = o0; out[t + 256] = o1; out[t + 512] = o2;
    short* ob = qbf + (size_t)row * kHID;
    ob[t] = f2bf(o0); ob[t + 256] = f2bf(o1); ob[t + 512] = f2bf(o2);
  } else {
    float* out = ekv + ((size_t)b * kL + kSE + s) * kHID;
    out[t] = o0; out[t + 256] = o1; out[t + 512] = o2;
  }
}

// ---------------------------------------------------------------------------
// Kernel 1b: pack (am & dm & ~eye) into bit-mask words [B][S][32] u64.
// One wave per (b,s) row; __ballot builds one 64-key word per iteration.
// ---------------------------------------------------------------------------
__global__ __launch_bounds__(64) void mask_pack_kernel(
    const unsigned char* __restrict__ am, const unsigned char* __restrict__ dm,
    unsigned long long* __restrict__ pmask)
{
  const int row = blockIdx.x;            // b*2048 + s
  const int b = row >> 11, s = row & 2047;
  const int lane = threadIdx.x;
  const unsigned char* dmr = dm + (size_t)row * kS;
  const unsigned char* amr = am + (size_t)b * kS;
  #pragma unroll 4
  for (int w = 0; w < 32; w++) {
    const int le = w * 64 + lane;
    const bool v = amr[le] && dmr[le] && (s != le);
    const unsigned long long word = __ballot(v);
    if (lane == 0) pmask[(size_t)row * 32 + w] = word;
  }
}

// ---------------------------------------------------------------------------
// Kernel 2/4: fp32 GEMM  C[M,N] = A[M,768] * W[N,768]^T + bias (+ residual)
// MODE 0: epilogue emits bf16 K [B,H,L,D] and bf16 V^T [B,H,D,L].
// MODE 1: +bias+residual -> fp32 out.
// ---------------------------------------------------------------------------
template <int MODE>
__global__ __launch_bounds__(256) void gemm64(
    const float* __restrict__ A, const float* __restrict__ W,
    const float* __restrict__ bias, float* __restrict__ outf,
    short* __restrict__ kb, short* __restrict__ vt,
    const float* __restrict__ resid)
{
  __shared__ float As[32][64];   // k-major
  __shared__ float Bs[32][64];
  const int t = threadIdx.x;
  const int m0 = blockIdx.x * 64, n0 = blockIdx.y * 64;
  const int tx = t & 15, ty = t >> 4;

  float acc[4][4] = {};

  for (int kt = 0; kt < kHID; kt += 32) {
    __syncthreads();
    #pragma unroll
    for (int r = 0; r < 2; r++) {
      const int f = t + r * 256;          // 0..511
      const int row = f >> 3, kc = f & 7;
      float4 va = *(const float4*)(A + (size_t)(m0 + row) * kHID + kt + kc * 4);
      As[kc * 4 + 0][row] = va.x; As[kc * 4 + 1][row] = va.y;
      As[kc * 4 + 2][row] = va.z; As[kc * 4 + 3][row] = va.w;
      float4 vb = *(const float4*)(W + (size_t)(n0 + row) * kHID + kt + kc * 4);
      Bs[kc * 4 + 0][row] = vb.x; Bs[kc * 4 + 1][row] = vb.y;
      Bs[kc * 4 + 2][row] = vb.z; Bs[kc * 4 + 3][row] = vb.w;
    }
    __syncthreads();
    #pragma unroll
    for (int k = 0; k < 32; k++) {
      const float4 a4 = *(const float4*)&As[k][ty * 4];
      const float4 b4 = *(const float4*)&Bs[k][tx * 4];
      const float av[4] = {a4.x, a4.y, a4.z, a4.w};
      const float bv[4] = {b4.x, b4.y, b4.z, b4.w};
      #pragma unroll
      for (int i = 0; i < 4; i++)
        #pragma unroll
        for (int j = 0; j < 4; j++)
          acc[i][j] += av[i] * bv[j];
    }
  }

  const int nb = n0 + tx * 4;
  const float4 bv4 = *(const float4*)(bias + nb);
  const float bvv[4] = {bv4.x, bv4.y, bv4.z, bv4.w};

  if (MODE == 0) {
    const bool isV = nb >= kHID;
    const int nn = isV ? nb - kHID : nb;
    const int h = nn >> 6, d0 = nn & 63;
    const int bb = m0 >> 12;               // 64-row blocks never straddle b
    if (!isV) {
      #pragma unroll
      for (int i = 0; i < 4; i++) {
        const int m = m0 + ty * 4 + i;
        const int l = m & 4095;
        short4 o = {f2bf(acc[i][0] + bvv[0]), f2bf(acc[i][1] + bvv[1]),
                    f2bf(acc[i][2] + bvv[2]), f2bf(acc[i][3] + bvv[3])};
        *(short4*)(kb + (((size_t)(bb * kH + h)) * kL + l) * kD + d0) = o;
      }
    } else {
      const int l0 = m0 + ty * 4;
      const int lloc = l0 & 4095;
      #pragma unroll
      for (int j = 0; j < 4; j++) {
        short4 o = {f2bf(acc[0][j] + bvv[j]), f2bf(acc[1][j] + bvv[j]),
                    f2bf(acc[2][j] + bvv[j]), f2bf(acc[3][j] + bvv[j])};
        *(short4*)(vt + (((size_t)(bb * kH + h)) * kD + d0 + j) * kL + lloc) = o;
      }
    }
  } else {
    #pragma unroll
    for (int i = 0; i < 4; i++) {
      const int m = m0 + ty * 4 + i;
      const size_t off = (size_t)m * kHID + nb;
      const float4 r4 = *(const float4*)(resid + off);
      float4 o = {acc[i][0] + bvv[0] + r4.x, acc[i][1] + bvv[1] + r4.y,
                  acc[i][2] + bvv[2] + r4.z, acc[i][3] + bvv[3] + r4.w};
      *(float4*)(outf + off) = o;
    }
  }
}

// ---------------------------------------------------------------------------
// Kernel 3: flash attention with MFMA 16x16x32 bf16, fp32 softmax/accum.
// grid = (S/64, H, B); block = 256 (4 waves). Each wave owns 16 q-rows.
// K tile [64l][64d] and V^T tile [64d][64l] staged in LDS, 16B-chunk
// XOR-swizzled by (row&7). P staged per-wave in LDS (bf16, same swizzle).
// C/D layout (m89): col = lane&15, row = (lane>>4)*4 + reg.
// ---------------------------------------------------------------------------
__global__ __launch_bounds__(256) void attn_mfma(
    const short* __restrict__ qbf, const short* __restrict__ kbuf,
    const short* __restrict__ vtbuf, const unsigned long long* __restrict__ pmask,
    float* __restrict__ attn_out)
{
  __shared__ short Ks[64 * 64];
  __shared__ short Vs[64 * 64];
  __shared__ short Ps[4][16 * 64];

  const int qt = blockIdx.x, h = blockIdx.y, b = blockIdx.z;
  const int s0 = qt * 64;
  const int t = threadIdx.x;
  const int wv = t >> 6, lane = t & 63;
  const int g = lane >> 4, ln = lane & 15;
  const float scale = 0.125f;     // 1/sqrt(64)

  const short* Kg = kbuf + ((size_t)(b * kH + h)) * kL * kD;
  const short* Vg = vtbuf + ((size_t)(b * kH + h)) * kD * kL;

  // Q fragments (A-operand), held in registers for the whole kernel.
  const short* qrow = qbf + ((size_t)(b * kS + s0 + wv * 16 + ln)) * kHID + h * kD;
  const bfrag aQ0 = *(const bfrag*)(qrow + g * 8);
  const bfrag aQ1 = *(const bfrag*)(qrow + 32 + g * 8);

  // staging coords: thread t covers row srow, 32-byte pair sc4
  const int srow = t >> 2, sc4 = t & 3;
  const int c0 = sc4 * 2, c1 = c0 + 1;
  const int swz0 = srow * 64 + ((c0 ^ (srow & 7)) << 3);
  const int swz1 = srow * 64 + ((c1 ^ (srow & 7)) << 3);

  f32x4 accO[4] = {};             // [nt] over d; reg r = q-sub-row
  float mrun[4] = {-FLT_MAX, -FLT_MAX, -FLT_MAX, -FLT_MAX};
  float lrun[4] = {0.f, 0.f, 0.f, 0.f};
  const f32x4 zero = {0.f, 0.f, 0.f, 0.f};

  for (int lt = 0; lt < kL / 64; lt++) {
    __syncthreads();
    {
      const short* kgp = Kg + ((size_t)(lt * 64 + srow)) * kD + sc4 * 16;
      uint4 ka = *(const uint4*)kgp;
      uint4 kb2 = *(const uint4*)(kgp + 8);
      *(uint4*)&Ks[swz0] = ka;
      *(uint4*)&Ks[swz1] = kb2;
      const short* vgp = Vg + (size_t)srow * kL + lt * 64 + sc4 * 16;
      uint4 va = *(const uint4*)vgp;
      uint4 vb = *(const uint4*)(vgp + 8);
      *(uint4*)&Vs[swz0] = va;
      *(uint4*)&Vs[swz1] = vb;
    }
    __syncthreads();

    // ---- QK^T: accS[nt] = S[16q x 16l] ----
    f32x4 accS[4];
    #pragma unroll
    for (int nt = 0; nt < 4; nt++) {
      const int row = nt * 16 + ln;
      const bfrag bK0 = *(const bfrag*)&Ks[row * 64 + (((g + 0) ^ (ln & 7)) << 3)];
      const bfrag bK1 = *(const bfrag*)&Ks[row * 64 + (((g + 4) ^ (ln & 7)) << 3)];
      accS[nt] = __builtin_amdgcn_mfma_f32_16x16x32_bf16(aQ0, bK0, zero, 0, 0, 0);
      accS[nt] = __builtin_amdgcn_mfma_f32_16x16x32_bf16(aQ1, bK1, accS[nt], 0, 0, 0);
    }

    // ---- scale + mask ----
    if (lt >= kSE / 64) {
      #pragma unroll
      for (int r = 0; r < 4; r++) {
        const int q = s0 + wv * 16 + g * 4 + r;
        const unsigned long long wmask =
            pmask[((size_t)(b * kS + q)) * 32 + (lt - kSE / 64)];
        #pragma unroll
        for (int nt = 0; nt < 4; nt++) {
          const bool valid = (wmask >> (nt * 16 + ln)) & 1ull;
          accS[nt][r] = valid ? accS[nt][r] * scale : -FLT_MAX;
        }
      }
    } else {
      #pragma unroll
      for (int nt = 0; nt < 4; nt++)
        #pragma unroll
        for (int r = 0; r < 4; r++) accS[nt][r] *= scale;
    }

    // ---- online softmax (per q-row r; row-mates are lanes xor 1,2,4,8) ----
    float corr[4];
    #pragma unroll
    for (int r = 0; r < 4; r++) {
      float tm = fmaxf(fmaxf(accS[0][r], accS[1][r]), fmaxf(accS[2][r], accS[3][r]));
      #pragma unroll
      for (int mk = 1; mk < 16; mk <<= 1) tm = fmaxf(tm, __shfl_xor(tm, mk, 64));
      const float mn = fmaxf(mrun[r], tm);
      corr[r] = __expf(mrun[r] - mn);
      mrun[r] = mn;
      float ps = 0.f;
      #pragma unroll
      for (int nt = 0; nt < 4; nt++) {
        const float p = __expf(accS[nt][r] - mn);
        accS[nt][r] = p;
        ps += p;
      }
      #pragma unroll
      for (int mk = 1; mk < 16; mk <<= 1) ps += __shfl_xor(ps, mk, 64);
      lrun[r] = lrun[r] * corr[r] + ps;
      // write P row (bf16, swizzled)
      const int prow = g * 4 + r;
      #pragma unroll
      for (int nt = 0; nt < 4; nt++) {
        const int l = nt * 16 + ln;
        Ps[wv][prow * 64 + (((l >> 3) ^ (prow & 7)) << 3) + (l & 7)] = f2bf(accS[nt][r]);
      }
    }

    // ---- rescale O ----
    #pragma unroll
    for (int nt = 0; nt < 4; nt++) {
      f32x4 a = accO[nt];
      a[0] *= corr[0]; a[1] *= corr[1]; a[2] *= corr[2]; a[3] *= corr[3];
      accO[nt] = a;
    }

    // ---- PV: O += P[16q x 64l] * V[64l x 64d] (B = V^T rows) ----
    const bfrag aP0 = *(const bfrag*)&Ps[wv][ln * 64 + (((g + 0) ^ (ln & 7)) << 3)];
    const bfrag aP1 = *(const bfrag*)&Ps[wv][ln * 64 + (((g + 4) ^ (ln & 7)) << 3)];
    #pragma unroll
    for (int nt = 0; nt < 4; nt++) {
      const int row = nt * 16 + ln;
      const bfrag bV0 = *(const bfrag*)&Vs[row * 64 + (((g + 0) ^ (ln & 7)) << 3)];
      const bfrag bV1 = *(const bfrag*)&Vs[row * 64 + (((g + 4) ^ (ln & 7)) << 3)];
      accO[nt] = __builtin_amdgcn_mfma_f32_16x16x32_bf16(aP0, bV0, accO[nt], 0, 0, 0);
      accO[nt] = __builtin_amdgcn_mfma_f32_16x16x32_bf16(aP1, bV1, accO[nt], 0, 0, 0);
    }
  }

  // ---- normalize + store ----
  float inv[4];
  #pragma unroll
  for (int r = 0; r < 4; r++) inv[r] = 1.0f / lrun[r];
  #pragma unroll
  for (int nt = 0; nt < 4; nt++)
    #pragma unroll
    for (int r = 0; r < 4; r++) {
      const int q = s0 + wv * 16 + g * 4 + r;
      attn_out[((size_t)(b * kS + q)) * kHID + h * kD + nt * 16 + ln] =
          accO[nt][r] * inv[r];
    }
}

// ---------------------------------------------------------------------------
extern "C" void kernel_launch(void* const* d_in, const int* in_sizes, int n_in,
                              void* d_out, int out_size, void* d_ws, size_t ws_size,
                              hipStream_t stream) {
  const float* q_in    = (const float*)d_in[0];
  const float* kv_in   = (const float*)d_in[1];
  const float* enc     = (const float*)d_in[2];
  const unsigned char* am = (const unsigned char*)d_in[3];   // bool -> 1 byte
  const unsigned char* dm = (const unsigned char*)d_in[4];   // bool -> 1 byte
  // d_in[5], d_in[6]: Wq (computed-then-discarded in reference) -> skipped
  const float* wkv_w   = (const float*)d_in[7];
  const float* wkv_b   = (const float*)d_in[8];
  const float* dense_w = (const float*)d_in[9];
  const float* dense_b = (const float*)d_in[10];
  const float* norm_g  = (const float*)d_in[11];
  const float* norm_b  = (const float*)d_in[12];
  float* out = (float*)d_out;

  float* ws = (float*)d_ws;
  float* q_hs = ws;                                  // [B,S,HID] f32   3,145,728 f
  float* ekv  = ws + 3145728;                        // [B,L,HID] f32   6,291,456 f
  short* kbuf = (short*)(ws + 9437184);              // [B,H,L,D] bf16  (3,145,728 f)
  short* vtbuf = (short*)(ws + 12582912);            // [B,H,D,L] bf16  (3,145,728 f)
  short* qbf  = (short*)(ws + 15728640);             // [B,S,HID] bf16  (1,572,864 f)
  unsigned long long* pmask = (unsigned long long*)(ws + 17301504); // [B,S,32] u64
  float* attn_out = ekv;                             // alias: ekv dead after KV GEMM

  hipLaunchKernelGGL(ln_copy_kernel, dim3(kB * kS, 3), dim3(256), 0, stream,
                     q_in, kv_in, enc, norm_g, norm_b, q_hs, ekv, qbf);
  hipLaunchKernelGGL(mask_pack_kernel, dim3(kB * kS), dim3(64), 0, stream,
                     am, dm, pmask);
  hipLaunchKernelGGL((gemm64<0>), dim3((kB * kL) / 64, (2 * kHID) / 64), dim3(256), 0, stream,
                     ekv, wkv_w, wkv_b, nullptr, kbuf, vtbuf, nullptr);
  hipLaunchKernelGGL(attn_mfma, dim3(kS / 64, kH, kB), dim3(256), 0, stream,
                     qbf, kbuf, vtbuf, pmask, attn_out);
  hipLaunchKernelGGL((gemm64<1>), dim3((kB * kS) / 64, kHID / 64), dim3(256), 0, stream,
                     attn_out, dense_w, dense_b, out, nullptr, nullptr, q_hs);
}

// Round 5
// 492.680 us; speedup vs baseline: 3.0067x; 1.4103x over previous
//
#include <hip/hip_runtime.h>
#include <float.h>

// Problem constants
constexpr int kB = 2, kS = 2048, kSE = 2048, kL = 4096, kHID = 768, kH = 12, kD = 64;

typedef __attribute__((ext_vector_type(8))) short bfrag;   // 8 bf16 (4 VGPRs)
typedef __attribute__((ext_vector_type(4))) float f32x4;   // 4 fp32 acc

__device__ __forceinline__ short f2bf(float x) {
  unsigned u = __float_as_uint(x);
  u += 0x7fffu + ((u >> 16) & 1u);     // RNE
  return (short)(u >> 16);
}

// ---------------------------------------------------------------------------
// Kernel 1: LayerNorm (q and kv) + copy encoder_output into bf16 ekv buffer.
// mode 0: LN(q) -> q_hs (f32, residual) + qbf (bf16, attention A-operand)
// mode 1: LN(kv) -> ekv_bf[:, SE+s, :]
// mode 2: enc -> ekv_bf[:, s, :]
// ---------------------------------------------------------------------------
__global__ __launch_bounds__(256) void ln_copy_kernel(
    const float* __restrict__ qin, const float* __restrict__ kvin,
    const float* __restrict__ enc, const float* __restrict__ g,
    const float* __restrict__ beta, float* __restrict__ q_hs,
    short* __restrict__ ekv, short* __restrict__ qbf)
{
  const int row = blockIdx.x;            // b*2048 + s
  const int mode = blockIdx.y;
  const int t = threadIdx.x;
  const int b = row >> 11, s = row & 2047;

  if (mode == 2) {
    const float4* src = (const float4*)(enc + (size_t)row * kHID);
    short* dst = ekv + ((size_t)b * kL + s) * kHID;
    if (t < 192) {
      float4 v = src[t];
      short4 o = {f2bf(v.x), f2bf(v.y), f2bf(v.z), f2bf(v.w)};
      *(short4*)(dst + t * 4) = o;
    }
    return;
  }

  const float* x = (mode == 0 ? qin : kvin) + (size_t)row * kHID;
  float v0 = x[t], v1 = x[t + 256], v2 = x[t + 512];
  float sum = v0 + v1 + v2;
  float sq  = v0 * v0 + v1 * v1 + v2 * v2;
  #pragma unroll
  for (int off = 32; off > 0; off >>= 1) {
    sum += __shfl_down(sum, off, 64);
    sq  += __shfl_down(sq,  off, 64);
  }
  __shared__ float red[8];
  const int wave = t >> 6;
  if ((t & 63) == 0) { red[wave] = sum; red[wave + 4] = sq; }
  __syncthreads();
  const float tsum = red[0] + red[1] + red[2] + red[3];
  const float tsq  = red[4] + red[5] + red[6] + red[7];
  const float mu   = tsum * (1.0f / kHID);
  const float var  = tsq * (1.0f / kHID) - mu * mu;
  const float rstd = rsqrtf(var + 1e-12f);

  const float o0 = (v0 - mu) * rstd * g[t]       + beta[t];
  const float o1 = (v1 - mu) * rstd * g[t + 256] + beta[t + 256];
  const float o2 = (v2 - mu) * rstd * g[t + 512] + beta[t + 512];

  if (mode == 0) {
    float* out = q_hs + (size_t)row * kHID;
    out[t] = o0; out[t + 256] = o1; out[t + 512] = o2;
    short* ob = qbf + (size_t)row * kHID;
    ob[t] = f2bf(o0); ob[t + 256] = f2bf(o1); ob[t + 512] = f2bf(o2);
  } else {
    short* out = ekv + ((size_t)b * kL + kSE + s) * kHID;
    out[t] = f2bf(o0); out[t + 256] = f2bf(o1); out[t + 512] = f2bf(o2);
  }
}

// ---------------------------------------------------------------------------
// Kernel 1b: pack (am & dm & ~eye) into bit-mask words [B][S][32] u64.
// ---------------------------------------------------------------------------
__global__ __launch_bounds__(64) void mask_pack_kernel(
    const unsigned char* __restrict__ am, const unsigned char* __restrict__ dm,
    unsigned long long* __restrict__ pmask)
{
  const int row = blockIdx.x;            // b*2048 + s
  const int b = row >> 11, s = row & 2047;
  const int lane = threadIdx.x;
  const unsigned char* dmr = dm + (size_t)row * kS;
  const unsigned char* amr = am + (size_t)b * kS;
  #pragma unroll 4
  for (int w = 0; w < 32; w++) {
    const int le = w * 64 + lane;
    const bool v = amr[le] && dmr[le] && (s != le);
    const unsigned long long word = __ballot(v);
    if (lane == 0) pmask[(size_t)row * 32 + w] = word;
  }
}

// ---------------------------------------------------------------------------
// Kernel 1c: convert Wkv and dense_w to bf16 (one shot).
// ---------------------------------------------------------------------------
__global__ __launch_bounds__(256) void cvt_w_kernel(
    const float* __restrict__ w1, const float* __restrict__ w2,
    short* __restrict__ o1, short* __restrict__ o2)
{
  const int n1 = 2 * kHID * kHID;        // 1,179,648
  const int n2 = kHID * kHID;            //   589,824
  const int tot = (n1 + n2) / 4;         //   442,368 float4 chunks
  for (int idx = blockIdx.x * 256 + threadIdx.x; idx < tot; idx += gridDim.x * 256) {
    const int i4 = idx * 4;
    if (i4 < n1) {
      float4 v = *(const float4*)(w1 + i4);
      short4 o = {f2bf(v.x), f2bf(v.y), f2bf(v.z), f2bf(v.w)};
      *(short4*)(o1 + i4) = o;
    } else {
      float4 v = *(const float4*)(w2 + (i4 - n1));
      short4 o = {f2bf(v.x), f2bf(v.y), f2bf(v.z), f2bf(v.w)};
      *(short4*)(o2 + (i4 - n1)) = o;
    }
  }
}

// ---------------------------------------------------------------------------
// Kernel 2/4: bf16 MFMA GEMM  C[M,N] = A[M,768] * W[N,768]^T (+bias ...)
// 128x128 tile, BK=64, 256 threads = 4 waves (2x2), each wave 64x64 (4x4
// fragments of 16x16x32). LDS 16B-chunk XOR-swizzled by (row&7) exactly as
// the verified attn_mfma pattern; fragment reads are 2-way aliased (free).
// MODE 0: K-projection  -> kb[B,H,L,D] bf16    (n0 = blockIdx.y*128)
// MODE 1: V-projection  -> vt[B,H,D,L] bf16    (n index + 768; swapped MFMA
//         operands so C-rows run over d and lanes over l -> coalesced V^T)
// MODE 2: dense + bias + resid -> fp32 out
// ---------------------------------------------------------------------------
template <int MODE>
__global__ __launch_bounds__(256) void gemm_mfma(
    const short* __restrict__ A, const short* __restrict__ W,
    const float* __restrict__ bias, short* __restrict__ kb,
    short* __restrict__ vt, float* __restrict__ outf,
    const float* __restrict__ resid)
{
  __shared__ short As[128 * 64];
  __shared__ short Bs[128 * 64];
  const int t = threadIdx.x;
  const int m0 = blockIdx.x * 128;
  const int n0 = blockIdx.y * 128 + (MODE == 1 ? kHID : 0);
  const int wv = t >> 6, lane = t & 63;
  const int g = lane >> 4, ln = lane & 15;
  const int wr = wv >> 1, wc = wv & 1;

  f32x4 acc[4][4] = {};   // MODE 0/2: [i=m-tile][j=n-tile]; MODE 1: [i=n][j=m]

  for (int kt = 0; kt < kHID; kt += 64) {
    // issue global loads early (reg-staged)
    uint4 ra[4], rb[4];
    #pragma unroll
    for (int r = 0; r < 4; r++) {
      const int f = t + r * 256;           // 0..1023
      const int row = f >> 3, c = f & 7;
      ra[r] = *(const uint4*)(A + (size_t)(m0 + row) * kHID + kt + c * 8);
      rb[r] = *(const uint4*)(W + (size_t)(n0 + row) * kHID + kt + c * 8);
    }
    __syncthreads();   // previous tile's compute done
    #pragma unroll
    for (int r = 0; r < 4; r++) {
      const int f = t + r * 256;
      const int row = f >> 3, c = f & 7;
      const int sc = c ^ (row & 7);
      *(uint4*)&As[row * 64 + sc * 8] = ra[r];
      *(uint4*)&Bs[row * 64 + sc * 8] = rb[r];
    }
    __syncthreads();

    bfrag a0[4], a1[4], b0[4], b1[4];
    #pragma unroll
    for (int i = 0; i < 4; i++) {
      const int ar = wr * 64 + i * 16 + ln;
      a0[i] = *(const bfrag*)&As[ar * 64 + (((g + 0) ^ (ln & 7)) << 3)];
      a1[i] = *(const bfrag*)&As[ar * 64 + (((g + 4) ^ (ln & 7)) << 3)];
      const int br = wc * 64 + i * 16 + ln;
      b0[i] = *(const bfrag*)&Bs[br * 64 + (((g + 0) ^ (ln & 7)) << 3)];
      b1[i] = *(const bfrag*)&Bs[br * 64 + (((g + 4) ^ (ln & 7)) << 3)];
    }
    #pragma unroll
    for (int i = 0; i < 4; i++)
      #pragma unroll
      for (int j = 0; j < 4; j++) {
        if (MODE == 1) {   // swapped: A-operand = W fragment
          acc[i][j] = __builtin_amdgcn_mfma_f32_16x16x32_bf16(b0[i], a0[j], acc[i][j], 0, 0, 0);
          acc[i][j] = __builtin_amdgcn_mfma_f32_16x16x32_bf16(b1[i], a1[j], acc[i][j], 0, 0, 0);
        } else {
          acc[i][j] = __builtin_amdgcn_mfma_f32_16x16x32_bf16(a0[i], b0[j], acc[i][j], 0, 0, 0);
          acc[i][j] = __builtin_amdgcn_mfma_f32_16x16x32_bf16(a1[i], b1[j], acc[i][j], 0, 0, 0);
        }
      }
  }

  // C/D layout (m89): col = lane&15, row = (lane>>4)*4 + reg
  if (MODE == 0) {
    #pragma unroll
    for (int j = 0; j < 4; j++) {
      const int n = n0 + wc * 64 + j * 16 + ln;       // < 768
      const float bn = bias[n];
      const int h = n >> 6, d = n & 63;
      #pragma unroll
      for (int i = 0; i < 4; i++)
        #pragma unroll
        for (int r = 0; r < 4; r++) {
          const int m = m0 + wr * 64 + i * 16 + g * 4 + r;
          kb[(((size_t)((m >> 12) * kH + h)) * kL + (m & 4095)) * kD + d] =
              f2bf(acc[i][j][r] + bn);
        }
    }
  } else if (MODE == 1) {
    #pragma unroll
    for (int i = 0; i < 4; i++)
      #pragma unroll
      for (int r = 0; r < 4; r++) {
        const int n = n0 + wc * 64 + i * 16 + g * 4 + r;   // >= 768
        const float bn = bias[n];
        const int nn = n - kHID;
        const int h = nn >> 6, d = nn & 63;
        #pragma unroll
        for (int j = 0; j < 4; j++) {
          const int m = m0 + wr * 64 + j * 16 + ln;
          vt[(((size_t)((m >> 12) * kH + h)) * kD + d) * kL + (m & 4095)] =
              f2bf(acc[i][j][r] + bn);
        }
      }
  } else {
    #pragma unroll
    for (int j = 0; j < 4; j++) {
      const int n = n0 + wc * 64 + j * 16 + ln;
      const float bn = bias[n];
      #pragma unroll
      for (int i = 0; i < 4; i++)
        #pragma unroll
        for (int r = 0; r < 4; r++) {
          const int m = m0 + wr * 64 + i * 16 + g * 4 + r;
          const size_t off = (size_t)m * kHID + n;
          outf[off] = acc[i][j][r] + bn + resid[off];
        }
    }
  }
}

// ---------------------------------------------------------------------------
// Kernel 3: flash attention with MFMA 16x16x32 bf16, fp32 softmax/accum.
// (unchanged from R3 except output is bf16 for the dense MFMA GEMM)
// ---------------------------------------------------------------------------
__global__ __launch_bounds__(256) void attn_mfma(
    const short* __restrict__ qbf, const short* __restrict__ kbuf,
    const short* __restrict__ vtbuf, const unsigned long long* __restrict__ pmask,
    short* __restrict__ attn_out)
{
  __shared__ short Ks[64 * 64];
  __shared__ short Vs[64 * 64];
  __shared__ short Ps[4][16 * 64];

  const int qt = blockIdx.x, h = blockIdx.y, b = blockIdx.z;
  const int s0 = qt * 64;
  const int t = threadIdx.x;
  const int wv = t >> 6, lane = t & 63;
  const int g = lane >> 4, ln = lane & 15;
  const float scale = 0.125f;     // 1/sqrt(64)

  const short* Kg = kbuf + ((size_t)(b * kH + h)) * kL * kD;
  const short* Vg = vtbuf + ((size_t)(b * kH + h)) * kD * kL;

  const short* qrow = qbf + ((size_t)(b * kS + s0 + wv * 16 + ln)) * kHID + h * kD;
  const bfrag aQ0 = *(const bfrag*)(qrow + g * 8);
  const bfrag aQ1 = *(const bfrag*)(qrow + 32 + g * 8);

  const int srow = t >> 2, sc4 = t & 3;
  const int c0 = sc4 * 2, c1 = c0 + 1;
  const int swz0 = srow * 64 + ((c0 ^ (srow & 7)) << 3);
  const int swz1 = srow * 64 + ((c1 ^ (srow & 7)) << 3);

  f32x4 accO[4] = {};
  float mrun[4] = {-FLT_MAX, -FLT_MAX, -FLT_MAX, -FLT_MAX};
  float lrun[4] = {0.f, 0.f, 0.f, 0.f};
  const f32x4 zero = {0.f, 0.f, 0.f, 0.f};

  for (int lt = 0; lt < kL / 64; lt++) {
    __syncthreads();
    {
      const short* kgp = Kg + ((size_t)(lt * 64 + srow)) * kD + sc4 * 16;
      uint4 ka = *(const uint4*)kgp;
      uint4 kb2 = *(const uint4*)(kgp + 8);
      *(uint4*)&Ks[swz0] = ka;
      *(uint4*)&Ks[swz1] = kb2;
      const short* vgp = Vg + (size_t)srow * kL + lt * 64 + sc4 * 16;
      uint4 va = *(const uint4*)vgp;
      uint4 vb = *(const uint4*)(vgp + 8);
      *(uint4*)&Vs[swz0] = va;
      *(uint4*)&Vs[swz1] = vb;
    }
    __syncthreads();

    f32x4 accS[4];
    #pragma unroll
    for (int nt = 0; nt < 4; nt++) {
      const int row = nt * 16 + ln;
      const bfrag bK0 = *(const bfrag*)&Ks[row * 64 + (((g + 0) ^ (ln & 7)) << 3)];
      const bfrag bK1 = *(const bfrag*)&Ks[row * 64 + (((g + 4) ^ (ln & 7)) << 3)];
      accS[nt] = __builtin_amdgcn_mfma_f32_16x16x32_bf16(aQ0, bK0, zero, 0, 0, 0);
      accS[nt] = __builtin_amdgcn_mfma_f32_16x16x32_bf16(aQ1, bK1, accS[nt], 0, 0, 0);
    }

    if (lt >= kSE / 64) {
      #pragma unroll
      for (int r = 0; r < 4; r++) {
        const int q = s0 + wv * 16 + g * 4 + r;
        const unsigned long long wmask =
            pmask[((size_t)(b * kS + q)) * 32 + (lt - kSE / 64)];
        #pragma unroll
        for (int nt = 0; nt < 4; nt++) {
          const bool valid = (wmask >> (nt * 16 + ln)) & 1ull;
          accS[nt][r] = valid ? accS[nt][r] * scale : -FLT_MAX;
        }
      }
    } else {
      #pragma unroll
      for (int nt = 0; nt < 4; nt++)
        #pragma unroll
        for (int r = 0; r < 4; r++) accS[nt][r] *= scale;
    }

    float corr[4];
    #pragma unroll
    for (int r = 0; r < 4; r++) {
      float tm = fmaxf(fmaxf(accS[0][r], accS[1][r]), fmaxf(accS[2][r], accS[3][r]));
      #pragma unroll
      for (int mk = 1; mk < 16; mk <<= 1) tm = fmaxf(tm, __shfl_xor(tm, mk, 64));
      const float mn = fmaxf(mrun[r], tm);
      corr[r] = __expf(mrun[r] - mn);
      mrun[r] = mn;
      float ps = 0.f;
      #pragma unroll
      for (int nt = 0; nt < 4; nt++) {
        const float p = __expf(accS[nt][r] - mn);
        accS[nt][r] = p;
        ps += p;
      }
      #pragma unroll
      for (int mk = 1; mk < 16; mk <<= 1) ps += __shfl_xor(ps, mk, 64);
      lrun[r] = lrun[r] * corr[r] + ps;
      const int prow = g * 4 + r;
      #pragma unroll
      for (int nt = 0; nt < 4; nt++) {
        const int l = nt * 16 + ln;
        Ps[wv][prow * 64 + (((l >> 3) ^ (prow & 7)) << 3) + (l & 7)] = f2bf(accS[nt][r]);
      }
    }

    #pragma unroll
    for (int nt = 0; nt < 4; nt++) {
      f32x4 a = accO[nt];
      a[0] *= corr[0]; a[1] *= corr[1]; a[2] *= corr[2]; a[3] *= corr[3];
      accO[nt] = a;
    }

    const bfrag aP0 = *(const bfrag*)&Ps[wv][ln * 64 + (((g + 0) ^ (ln & 7)) << 3)];
    const bfrag aP1 = *(const bfrag*)&Ps[wv][ln * 64 + (((g + 4) ^ (ln & 7)) << 3)];
    #pragma unroll
    for (int nt = 0; nt < 4; nt++) {
      const int row = nt * 16 + ln;
      const bfrag bV0 = *(const bfrag*)&Vs[row * 64 + (((g + 0) ^ (ln & 7)) << 3)];
      const bfrag bV1 = *(const bfrag*)&Vs[row * 64 + (((g + 4) ^ (ln & 7)) << 3)];
      accO[nt] = __builtin_amdgcn_mfma_f32_16x16x32_bf16(aP0, bV0, accO[nt], 0, 0, 0);
      accO[nt] = __builtin_amdgcn_mfma_f32_16x16x32_bf16(aP1, bV1, accO[nt], 0, 0, 0);
    }
  }

  float inv[4];
  #pragma unroll
  for (int r = 0; r < 4; r++) inv[r] = 1.0f / lrun[r];
  #pragma unroll
  for (int nt = 0; nt < 4; nt++)
    #pragma unroll
    for (int r = 0; r < 4; r++) {
      const int q = s0 + wv * 16 + g * 4 + r;
      attn_out[((size_t)(b * kS + q)) * kHID + h * kD + nt * 16 + ln] =
          f2bf(accO[nt][r] * inv[r]);
    }
}

// ---------------------------------------------------------------------------
extern "C" void kernel_launch(void* const* d_in, const int* in_sizes, int n_in,
                              void* d_out, int out_size, void* d_ws, size_t ws_size,
                              hipStream_t stream) {
  const float* q_in    = (const float*)d_in[0];
  const float* kv_in   = (const float*)d_in[1];
  const float* enc     = (const float*)d_in[2];
  const unsigned char* am = (const unsigned char*)d_in[3];
  const unsigned char* dm = (const unsigned char*)d_in[4];
  // d_in[5], d_in[6]: Wq (computed-then-discarded in reference) -> skipped
  const float* wkv_w   = (const float*)d_in[7];
  const float* wkv_b   = (const float*)d_in[8];
  const float* dense_w = (const float*)d_in[9];
  const float* dense_b = (const float*)d_in[10];
  const float* norm_g  = (const float*)d_in[11];
  const float* norm_b  = (const float*)d_in[12];
  float* out = (float*)d_out;

  float* ws = (float*)d_ws;
  float* q_hs   = ws;                                 // f32 [B,S,HID]   3,145,728 f
  short* ekv    = (short*)(ws + 3145728);             // bf16 [B,L,HID]  (3,145,728 f)
  short* kbuf   = (short*)(ws + 6291456);             // bf16 [B,H,L,D]  (3,145,728 f)
  short* vtbuf  = (short*)(ws + 9437184);             // bf16 [B,H,D,L]  (3,145,728 f)
  short* qbf    = (short*)(ws + 12582912);            // bf16 [B,S,HID]  (1,572,864 f)
  unsigned long long* pmask = (unsigned long long*)(ws + 14155776); // [B,S,32] u64
  short* wkv_bf = (short*)(ws + 14417920);            // bf16 [1536,768] (589,824 f)
  short* wd_bf  = (short*)(ws + 15007744);            // bf16 [768,768]  (294,912 f)
  short* attn_bf = ekv;                               // alias: ekv dead after KV GEMM

  hipLaunchKernelGGL(ln_copy_kernel, dim3(kB * kS, 3), dim3(256), 0, stream,
                     q_in, kv_in, enc, norm_g, norm_b, q_hs, ekv, qbf);
  hipLaunchKernelGGL(mask_pack_kernel, dim3(kB * kS), dim3(64), 0, stream,
                     am, dm, pmask);
  hipLaunchKernelGGL(cvt_w_kernel, dim3(1024), dim3(256), 0, stream,
                     wkv_w, dense_w, wkv_bf, wd_bf);
  hipLaunchKernelGGL((gemm_mfma<0>), dim3(64, 6), dim3(256), 0, stream,
                     ekv, wkv_bf, wkv_b, kbuf, nullptr, nullptr, nullptr);
  hipLaunchKernelGGL((gemm_mfma<1>), dim3(64, 6), dim3(256), 0, stream,
                     ekv, wkv_bf, wkv_b, nullptr, vtbuf, nullptr, nullptr);
  hipLaunchKernelGGL(attn_mfma, dim3(kS / 64, kH, kB), dim3(256), 0, stream,
                     qbf, kbuf, vtbuf, pmask, attn_bf);
  hipLaunchKernelGGL((gemm_mfma<2>), dim3(32, 6), dim3(256), 0, stream,
                     attn_bf, wd_bf, dense_b, nullptr, nullptr, out, q_hs);
}